// Round 12
// baseline (198.143 us; speedup 1.0000x reference)
//
#include <hip/hip_runtime.h>
#include <hip/hip_bf16.h>
#include <math.h>

// Problem constants (from reference setup_inputs)
#define NPTS   65536
#define NGT    256
#define NCLS   80
#define TOPK   9
#define GSLICE 32                 // gts per filter block (grid.y = 8)
#define NPB    256                // points per filter block (grid.x = 256)
#define NXB    (NPTS / NPB)       // 256 point-chunks
#define SCAP   64                 // fixed per-(gt,chunk) bucket segment size
#define NSUB   4                  // select blocks per gt (fan-in in-dispatch)

// Workspace layout (no hot-path global atomics — rounds 3-5: 65K same-line
// global atomicAdds serialize at L2 for ~23 us; the NSUB fan-in below does
// only 1024 atomics on 256 addresses):
//   bucket : [NGT][NXB][SCAP] u64 = 33.55 MB (deterministic slot ranges,
//            FINAL rank keys — scoring fused into filter's copy-out)
//   counts : [NGT][NXB]       u16 = 128 KB   (written unconditionally)
//   partial: [NGT][NSUB][TOPK] u64 = 72 KB   (per-sub top-9, release-stored)
//   done   : [NGT] u32 = 1 KB                (zeroed by filter dispatch)
//
// Rank key: (sortable bits of L) << 32 | ~point_idx with
// L = 0.2*log2(sigmoid(cls)) + 0.8*log2(iou) — monotone transform of the
// reference score sigmoid^.2 * iou^.8, verified absmax 0.0 in rounds 1-11.
// u64-max == (higher score, lower index) == JAX top_k tie-break. Keys are
// unique within a gt (subs own disjoint point ranges; fillers differ in
// hi32) -> pop-argmax owners unique; all real/filler keys > 0, so 0 is the
// natural "empty".
//
// DISPATCH-COUNT LESSON (R10 vs R9/R11): 3-dispatch configs land 129-134,
// 2-dispatch 112-115 — a dispatch boundary costs ~15-20 us here. This round
// buys R10's 4-blocks/gt select parallelism WITHOUT the third dispatch via
// a last-block-done fan-in (device-scope release/acquire per G16).
__device__ inline unsigned long long pack_key(float L, unsigned idx) {
    unsigned u   = __float_as_uint(L);
    unsigned k32 = (u & 0x80000000u) ? ~u : (u | 0x80000000u);
    return ((unsigned long long)k32 << 32) | (unsigned)(~idx);
}

__device__ inline unsigned long long umax64(unsigned long long a,
                                            unsigned long long b) {
    return a > b ? a : b;
}

__device__ inline unsigned long long wave_max64(unsigned long long m) {
#pragma unroll
    for (int off = 1; off < 64; off <<= 1)
        m = umax64(m, (unsigned long long)__shfl_xor(m, off));
    return m;
}

// ---------------------------------------------------------------------------
// k1: filter + score + compact into deterministic per-(gt,chunk) segments.
// Bit-identical to rounds 8-11 (verified absmax 0.0) except the added
// done[]-zero (xb==0 blocks). Also zeroes w.
// ---------------------------------------------------------------------------
__global__ __launch_bounds__(256) void filter_kernel(
    const float* __restrict__ preds,          // [NPTS][4]
    const float* __restrict__ gtb,            // [NGT][4]
    const int*   __restrict__ glab,           // [NGT]
    const float* __restrict__ cls,            // [NPTS][NCLS]
    unsigned short* __restrict__ counts,      // [NGT][NXB]
    unsigned long long* __restrict__ bucket,  // [NGT][NXB][SCAP]
    unsigned* __restrict__ done,              // [NGT]
    float* __restrict__ w)                    // [NPTS]
{
    __shared__ unsigned lcnt[GSLICE];
    __shared__ int      glabs[GSLICE];
    __shared__ unsigned long long stage[GSLICE][SCAP]; // 16 KiB

    const int t   = threadIdx.x;
    const int xb  = blockIdx.x;                 // point chunk 0..255
    const int g0  = blockIdx.y * GSLICE;
    const int pt  = xb * NPB + t;
    const int bid = blockIdx.y * NXB + xb;      // 0..2047

    if (t < GSLICE) {
        lcnt[t]  = 0u;
        glabs[t] = glab[g0 + t];
        if (xb == 0) done[g0 + t] = 0u;         // visible to select (new dispatch)
    }
    if (t < 32) w[bid * 32 + t] = 0.0f;         // 2048 blocks x 32 = NPTS

    float4 pb = ((const float4*)preds)[pt];
    float parea = (pb.z - pb.x) * (pb.w - pb.y);
    __syncthreads();

    for (int gi = 0; gi < GSLICE; ++gi) {
        const float4 g4 = ((const float4*)gtb)[g0 + gi];  // uniform -> SGPR
        float ix1 = fmaxf(pb.x, g4.x), iy1 = fmaxf(pb.y, g4.y);
        float ix2 = fminf(pb.z, g4.z), iy2 = fminf(pb.w, g4.w);
        float iw  = fmaxf(ix2 - ix1, 0.0f);
        float ih  = fmaxf(iy2 - iy1, 0.0f);
        float inter = iw * ih;
        if (inter > 0.0f) {
            // bit-exact round-1 operand forms
            float garea = (g4.z - g4.x) * (g4.w - g4.y);
            float uni = fmaxf(parea + garea - inter, 1e-6f);
            float iou = inter / uni;
            unsigned long long entry =
                ((unsigned long long)__float_as_uint(iou) << 32) |
                (unsigned)(~(unsigned)pt);
            unsigned slot = atomicAdd(&lcnt[gi], 1u);   // LDS atomic only
            if (slot < SCAP) stage[gi][slot] = entry;
            // slot >= SCAP statistically unreachable (P ~ 2.5e-12/pair,
            // fixed input seed; never hit in rounds 1-11)
        }
    }
    __syncthreads();

    if (t < GSLICE) {
        unsigned c = lcnt[t];
        if (c > SCAP) c = SCAP;
        lcnt[t] = c;
        counts[(size_t)(g0 + t) * NXB + xb] = (unsigned short)c;
    }
    __syncthreads();

    // scoring copy-out: gathers + transcendentals only on the ~366 real
    // entries (exec-masked) — round 7 showed dense scoring is fatal.
    const float E1 = 1.0f - 0.8f;   // exact round-1 constant expression
#pragma unroll
    for (int k = 0; k < 8; k += 4) {
        unsigned long long e[4];
        bool  vld[4];
        int   gi[4];
        float x[4];
#pragma unroll
        for (int j = 0; j < 4; ++j) {
            int i = (k + j) * 256 + t;
            gi[j] = i >> 6;                 // uniform per wave
            int sl = i & (SCAP - 1);        // == lane
            e[j]   = stage[gi[j]][sl];
            vld[j] = sl < (int)lcnt[gi[j]];
        }
#pragma unroll
        for (int j = 0; j < 4; ++j) {
            if (vld[j]) {                   // exec-masked: no addr otherwise
                unsigned p = ~(unsigned)(e[j] & 0xFFFFFFFFu);
                x[j] = cls[(size_t)p * NCLS + glabs[gi[j]]];
            }
        }
#pragma unroll
        for (int j = 0; j < 4; ++j) {
            if (vld[j]) {
                float iou = __uint_as_float((unsigned)(e[j] >> 32));
                float s   = 1.0f / (1.0f + expf(-x[j]));
                float L   = E1 * log2f(s) + 0.8f * log2f(iou);
                unsigned u   = __float_as_uint(L);
                unsigned k32 = (u & 0x80000000u) ? ~u : (u | 0x80000000u);
                int i = (k + j) * 256 + t;
                bucket[((size_t)(g0 + gi[j]) * NXB + xb) * SCAP + (i & (SCAP - 1))]
                    = ((unsigned long long)k32 << 32) | (e[j] & 0xFFFFFFFFu);
            }
        }
    }
}

// ---------------------------------------------------------------------------
// k2: grid (NGT, NSUB) = 1024 blocks x 256 (4 blocks/CU — R9/R11's select at
// 1 block/CU sat at ~24 us, 3x its issue+BW model; R5/R6/R9 all show the
// 1-block/CU latency plateau). Per block: scan 4096 slots (wave-uniform
// counts), per-wave pop-argmax (verified R10/R11), wave-0 block merge
// (verified R11 phase B), release-store 9 keys, fence, done-counter. Last
// arriver per gt merges 36 partials + 9 fillers (pool bit-identical to
// rounds 1-11) and runs the verified Gaussian/atomicMax tail.
// ---------------------------------------------------------------------------
__global__ __launch_bounds__(256) void select_kernel(
    const unsigned short*     __restrict__ counts,  // [NGT][NXB]
    const unsigned long long* __restrict__ bucket,  // [NGT][NXB][SCAP]
    unsigned long long*       __restrict__ partial, // [NGT][NSUB][TOPK]
    unsigned*                 __restrict__ done,    // [NGT]
    const float* __restrict__ pts,                  // [NPTS][2]
    const float* __restrict__ gtb,                  // [NGT][4]
    float* __restrict__ w)                          // [NPTS]
{
    const int g    = blockIdx.x;
    const int sub  = blockIdx.y;                // 0..3
    const int t    = threadIdx.x;
    const int lane = t & 63;
    const int wid  = t >> 6;                    // 0..3

    __shared__ unsigned short scnt[64];
    __shared__ unsigned long long wl[4 * TOPK];
    __shared__ int islast_s;
    __shared__ unsigned tidx[TOPK];
    __shared__ float ppy[TOPK], ppx[TOPK];

    if (t < 64) scnt[t] = counts[(size_t)g * NXB + sub * 64 + t];
    __syncthreads();

    // ---- per-wave scan + pop-argmax (barrier-free; verified R10/R11) ----
    const unsigned long long* src =
        bucket + (size_t)g * (NXB * SCAP) + (size_t)sub * 4096;

    unsigned long long e[16];
#pragma unroll
    for (int k = 0; k < 16; k += 4) {
        unsigned long long v[4];
#pragma unroll
        for (int j = 0; j < 4; ++j) v[j] = src[(k + j) * 256 + t]; // coalesced
#pragma unroll
        for (int j = 0; j < 4; ++j) {
            int c = (int)scnt[(k + j) * 4 + wid];   // wave-uniform broadcast
            e[k + j] = (lane < c) ? v[j] : 0ULL;    // poison masked
        }
    }
    unsigned long long mymax = 0ULL;
#pragma unroll
    for (int j = 0; j < 16; ++j) mymax = umax64(mymax, e[j]);

#pragma unroll
    for (int r = 0; r < TOPK; ++r) {
        unsigned long long m = wave_max64(mymax);
        if (lane == 0) wl[wid * TOPK + r] = m;
        if (m != 0ULL && mymax == m) {              // unique owner pops
#pragma unroll
            for (int j = 0; j < 16; ++j) if (e[j] == m) e[j] = 0ULL;
            mymax = 0ULL;
#pragma unroll
            for (int j = 0; j < 16; ++j) mymax = umax64(mymax, e[j]);
        }
    }
    __syncthreads();

    // ---- wave 0: merge 36 wave-partials, publish block top-9, fan-in ----
    if (wid == 0) {
        unsigned long long f0 = (lane < 4 * TOPK) ? wl[lane] : 0ULL;
        unsigned long long mx = f0;
        unsigned long long out[TOPK];
#pragma unroll
        for (int r = 0; r < TOPK; ++r) {
            unsigned long long m = wave_max64(mx);
            out[r] = m;
            if (m != 0ULL && mx == m) { f0 = 0ULL; mx = 0ULL; }
            mx = f0;
        }
        if (lane == 0) {
            unsigned long long* dst = partial + ((size_t)g * NSUB + sub) * TOPK;
#pragma unroll
            for (int r = 0; r < TOPK; ++r)
                __hip_atomic_store(&dst[r], out[r], __ATOMIC_RELEASE,
                                   __HIP_MEMORY_SCOPE_AGENT);
            __threadfence();                        // device-scope drain (G16)
            unsigned old = atomicAdd(&done[g], 1u); // device scope by default
            islast_s = (old == NSUB - 1) ? 1 : 0;
        }
    }
    __syncthreads();

    if (!islast_s) return;                          // non-last blocks exit

    // ---- last arriver: final merge of NSUB*9 partials + 9 fillers ----
    if (wid == 0) {
        __threadfence();
        unsigned long long f[2];
        f[0] = (lane < NSUB * TOPK)
             ? __hip_atomic_load(&partial[(size_t)g * (NSUB * TOPK) + lane],
                                 __ATOMIC_ACQUIRE, __HIP_MEMORY_SCOPE_AGENT)
             : 0ULL;
        f[1] = (lane < TOPK) ? pack_key(-INFINITY, (unsigned)lane) : 0ULL;

        unsigned long long mx = umax64(f[0], f[1]);
#pragma unroll
        for (int r = 0; r < TOPK; ++r) {
            unsigned long long m = wave_max64(mx);  // >0: fillers guarantee 9
            if (lane == 0) tidx[r] = ~(unsigned)(m & 0xFFFFFFFFu);
            if (mx == m) {                          // unique owner pops
#pragma unroll
                for (int j = 0; j < 2; ++j) if (f[j] == m) f[j] = 0ULL;
                mx = umax64(f[0], f[1]);
            }
        }
    }
    __syncthreads();

    if (t < TOPK) {
        unsigned pi = tidx[t];
        ppy[t] = pts[2 * (size_t)pi];       // points col 0 ("cy" in reference)
        ppx[t] = pts[2 * (size_t)pi + 1];   // points col 1 ("cx")
    }
    __syncthreads();

    if (t == 0) {
        float4 g4 = ((const float4*)gtb)[g];
        float m0 = 0.0f, m1 = 0.0f;
#pragma unroll
        for (int k = 0; k < TOPK; ++k) { m0 += ppy[k]; m1 += ppx[k]; }
        m0 /= (float)TOPK; m1 /= (float)TOPK;

        float d0[TOPK], d1[TOPK];
        float a = 0.0f, bb = 0.0f, dd = 0.0f;
#pragma unroll
        for (int k = 0; k < TOPK; ++k) {
            d0[k] = ppy[k] - m0;
            d1[k] = ppx[k] - m1;
            a  += d0[k] * d0[k];
            bb += d0[k] * d1[k];
            dd += d1[k] * d1[k];
        }
        a /= (float)TOPK; bb /= (float)TOPK; dd /= (float)TOPK;
        float det  = a * dd - bb * bb;
        float rinv = 1.0f / (det + 1e-10f);

#pragma unroll
        for (int k = 0; k < TOPK; ++k) {
            float q = d0[k] * (dd * d0[k] - bb * d1[k])
                    + d1[k] * (a  * d1[k] - bb * d0[k]);
            float maha = q * rinv;
            float wt = expf(-0.5f * maha);
            bool valid = (ppx[k] - g4.x > 1e-10f) && (ppy[k] - g4.y > 1e-10f) &&
                         (g4.z - ppx[k] > 1e-10f) && (g4.w - ppy[k] > 1e-10f);
            float wv = valid ? wt : 0.0f;
            atomicMax((int*)&w[tidx[k]], __float_as_int(wv));
        }
    }
}

// ---------------------------------------------------------------------------
extern "C" void kernel_launch(void* const* d_in, const int* in_sizes, int n_in,
                              void* d_out, int out_size, void* d_ws, size_t ws_size,
                              hipStream_t stream) {
    const float* points  = (const float*)d_in[0];   // [65536,2]
    const float* cls     = (const float*)d_in[1];   // [65536,80]
    const float* preds   = (const float*)d_in[2];   // [65536,4]
    const float* gtb     = (const float*)d_in[3];   // [256,4]
    const int*   glab    = (const int*)d_in[4];     // [256]
    float* w = (float*)d_out;                       // [65536] f32

    char* ws = (char*)d_ws;
    unsigned long long* bucket = (unsigned long long*)ws;          // 33.55 MB
    size_t off = (size_t)NGT * NXB * SCAP * sizeof(unsigned long long);
    unsigned short* counts = (unsigned short*)(ws + off);          // 128 KB
    off += (size_t)NGT * NXB * sizeof(unsigned short);
    unsigned long long* partial = (unsigned long long*)(ws + off); // 72 KB
    off += (size_t)NGT * NSUB * TOPK * sizeof(unsigned long long);
    unsigned* done = (unsigned*)(ws + off);                        // 1 KB

    filter_kernel<<<dim3(NXB, NGT / GSLICE), 256, 0, stream>>>(
        preds, gtb, glab, cls, counts, bucket, done, w);
    select_kernel<<<dim3(NGT, NSUB), 256, 0, stream>>>(
        counts, bucket, partial, done, points, gtb, w);
}

// Round 13
// 114.326 us; speedup vs baseline: 1.7331x; 1.7331x over previous
//
#include <hip/hip_runtime.h>
#include <hip/hip_bf16.h>
#include <math.h>

// Problem constants (from reference setup_inputs)
#define NPTS   65536
#define NGT    256
#define NCLS   80
#define TOPK   9
#define GSLICE 32                 // gts per filter block (grid.y = 8)
#define NPB    256                // points per filter block (grid.x = 256)
#define NXB    (NPTS / NPB)       // 256 point-chunks
#define SCAP   64                 // fixed per-(gt,chunk) bucket segment size

// Workspace layout (no global atomics, no cross-block fences — R12's
// agent-scope release/acquire fan-in cost 107 us in L2 writeback/invalidate
// ops; R3-5's 65K same-line global atomicAdds cost ~23 us):
//   bucket : [NGT][NXB][SCAP] u64 = 33.55 MB (deterministic slot ranges,
//            FINAL rank keys — scoring fused into filter's copy-out)
//   counts : [NGT][NXB]       u16 = 128 KB   (written unconditionally)
//
// Rank key: (sortable bits of L) << 32 | ~point_idx with
// L = 0.2*log2(sigmoid(cls)) + 0.8*log2(iou) — monotone transform of the
// reference score sigmoid^.2 * iou^.8, verified absmax 0.0 in rounds 1-12.
// u64-max == (higher score, lower index) == JAX top_k tie-break. Keys
// unique per gt -> pop-argmax owners unique; all real/filler keys > 0.
//
// DISPATCH LESSONS: 2 dispatches = 112-115 us; 3 dispatches = 129-134;
// in-dispatch cross-XCD fan-in = 198. Two dispatches is the shape.
__device__ inline unsigned long long pack_key(float L, unsigned idx) {
    unsigned u   = __float_as_uint(L);
    unsigned k32 = (u & 0x80000000u) ? ~u : (u | 0x80000000u);
    return ((unsigned long long)k32 << 32) | (unsigned)(~idx);
}

__device__ inline unsigned long long umax64(unsigned long long a,
                                            unsigned long long b) {
    return a > b ? a : b;
}

__device__ inline unsigned long long wave_max64(unsigned long long m) {
#pragma unroll
    for (int off = 1; off < 64; off <<= 1)
        m = umax64(m, (unsigned long long)__shfl_xor(m, off));
    return m;
}

// ---------------------------------------------------------------------------
// k1: filter + score + compact into deterministic per-(gt,chunk) segments.
// Bit-identical to rounds 8-11 (verified absmax 0.0). Also zeroes w.
// ---------------------------------------------------------------------------
__global__ __launch_bounds__(256) void filter_kernel(
    const float* __restrict__ preds,          // [NPTS][4]
    const float* __restrict__ gtb,            // [NGT][4]
    const int*   __restrict__ glab,           // [NGT]
    const float* __restrict__ cls,            // [NPTS][NCLS]
    unsigned short* __restrict__ counts,      // [NGT][NXB]
    unsigned long long* __restrict__ bucket,  // [NGT][NXB][SCAP]
    float* __restrict__ w)                    // [NPTS]
{
    __shared__ unsigned lcnt[GSLICE];
    __shared__ int      glabs[GSLICE];
    __shared__ unsigned long long stage[GSLICE][SCAP]; // 16 KiB

    const int t   = threadIdx.x;
    const int xb  = blockIdx.x;                 // point chunk 0..255
    const int g0  = blockIdx.y * GSLICE;
    const int pt  = xb * NPB + t;
    const int bid = blockIdx.y * NXB + xb;      // 0..2047

    if (t < GSLICE) {
        lcnt[t]  = 0u;
        glabs[t] = glab[g0 + t];
    }
    if (t < 32) w[bid * 32 + t] = 0.0f;         // 2048 blocks x 32 = NPTS

    float4 pb = ((const float4*)preds)[pt];
    float parea = (pb.z - pb.x) * (pb.w - pb.y);
    __syncthreads();

    for (int gi = 0; gi < GSLICE; ++gi) {
        const float4 g4 = ((const float4*)gtb)[g0 + gi];  // uniform -> SGPR
        float ix1 = fmaxf(pb.x, g4.x), iy1 = fmaxf(pb.y, g4.y);
        float ix2 = fminf(pb.z, g4.z), iy2 = fminf(pb.w, g4.w);
        float iw  = fmaxf(ix2 - ix1, 0.0f);
        float ih  = fmaxf(iy2 - iy1, 0.0f);
        float inter = iw * ih;
        if (inter > 0.0f) {
            // bit-exact round-1 operand forms
            float garea = (g4.z - g4.x) * (g4.w - g4.y);
            float uni = fmaxf(parea + garea - inter, 1e-6f);
            float iou = inter / uni;
            unsigned long long entry =
                ((unsigned long long)__float_as_uint(iou) << 32) |
                (unsigned)(~(unsigned)pt);
            unsigned slot = atomicAdd(&lcnt[gi], 1u);   // LDS atomic only
            if (slot < SCAP) stage[gi][slot] = entry;
            // slot >= SCAP statistically unreachable (P ~ 2.5e-12/pair,
            // fixed input seed; never hit in rounds 1-12)
        }
    }
    __syncthreads();

    if (t < GSLICE) {
        unsigned c = lcnt[t];
        if (c > SCAP) c = SCAP;
        lcnt[t] = c;
        counts[(size_t)(g0 + t) * NXB + xb] = (unsigned short)c;
    }
    __syncthreads();

    // scoring copy-out: gathers + transcendentals only on the ~366 real
    // entries (exec-masked) — round 7 showed dense scoring is fatal.
    const float E1 = 1.0f - 0.8f;   // exact round-1 constant expression
#pragma unroll
    for (int k = 0; k < 8; k += 4) {
        unsigned long long e[4];
        bool  vld[4];
        int   gi[4];
        float x[4];
#pragma unroll
        for (int j = 0; j < 4; ++j) {
            int i = (k + j) * 256 + t;
            gi[j] = i >> 6;                 // uniform per wave
            int sl = i & (SCAP - 1);        // == lane
            e[j]   = stage[gi[j]][sl];
            vld[j] = sl < (int)lcnt[gi[j]];
        }
#pragma unroll
        for (int j = 0; j < 4; ++j) {
            if (vld[j]) {                   // exec-masked: no addr otherwise
                unsigned p = ~(unsigned)(e[j] & 0xFFFFFFFFu);
                x[j] = cls[(size_t)p * NCLS + glabs[gi[j]]];
            }
        }
#pragma unroll
        for (int j = 0; j < 4; ++j) {
            if (vld[j]) {
                float iou = __uint_as_float((unsigned)(e[j] >> 32));
                float s   = 1.0f / (1.0f + expf(-x[j]));
                float L   = E1 * log2f(s) + 0.8f * log2f(iou);
                unsigned u   = __float_as_uint(L);
                unsigned k32 = (u & 0x80000000u) ? ~u : (u | 0x80000000u);
                int i = (k + j) * 256 + t;
                bucket[((size_t)(g0 + gi[j]) * NXB + xb) * SCAP + (i & (SCAP - 1))]
                    = ((unsigned long long)k32 << 32) | (e[j] & 0xFFFFFFFFu);
            }
        }
    }
}

// ---------------------------------------------------------------------------
// k2: per gt (1024 threads, 16 waves) — R11's structure with one change:
// ALL 16 slot-loads hoisted as 8 independent ulonglong2 (dwordx4) loads
// issued before any use (R9/R11 strip-mined x4 -> only 64 lines/CU in
// flight; bucket is L3/HBM-resident [FETCH 17 MB of 33.5], latency ~500-900
// cyc under-covered -> the stuck ~22 us). Then per-wave 9-round pop-argmax
// (verified R10-R12), ONE barrier, wave-0 merge of 144 partials + 9 fillers
// (verified R11), and the verified Gaussian/atomicMax tail.
// ---------------------------------------------------------------------------
__global__ __launch_bounds__(1024) void select_kernel(
    const unsigned short*     __restrict__ counts,  // [NGT][NXB]
    const unsigned long long* __restrict__ bucket,  // [NGT][NXB][SCAP]
    const float* __restrict__ pts,                  // [NPTS][2]
    const float* __restrict__ gtb,                  // [NGT][4]
    float* __restrict__ w)                          // [NPTS]
{
    const int g    = blockIdx.x;
    const int t    = threadIdx.x;
    const int lane = t & 63;
    const int wid  = t >> 6;                        // 16 waves

    __shared__ unsigned short scnt[NXB];            // 512 B
    __shared__ unsigned long long wl[16 * TOPK];    // 144 partial keys
    __shared__ unsigned tidx[TOPK];
    __shared__ float ppy[TOPK], ppx[TOPK];

    if (t < NXB) scnt[t] = counts[(size_t)g * NXB + t];
    __syncthreads();

    // ---- scan: 8 x ulonglong2, ALL issued before first use ----
    const ulonglong2* src2 =
        (const ulonglong2*)(bucket + (size_t)g * (NXB * SCAP));
    ulonglong2 v[8];
#pragma unroll
    for (int k = 0; k < 8; ++k) v[k] = src2[k * 1024 + t];   // coalesced 16B

    unsigned long long e[16];
#pragma unroll
    for (int k = 0; k < 8; ++k) {
        int s0  = (k * 1024 + t) * 2;               // even slot index
        int c   = (int)scnt[s0 >> 6];               // segment count (LDS)
        int l0  = s0 & (SCAP - 1);                  // even: l0 and l0+1 pair
        e[2 * k]     = (l0     < c) ? v[k].x : 0ULL;  // poison masked
        e[2 * k + 1] = (l0 + 1 < c) ? v[k].y : 0ULL;
    }
    unsigned long long mymax = 0ULL;
#pragma unroll
    for (int j = 0; j < 16; ++j) mymax = umax64(mymax, e[j]);

    // ---- per-wave 9-round pop-argmax (barrier-free) ----
#pragma unroll
    for (int r = 0; r < TOPK; ++r) {
        unsigned long long m = wave_max64(mymax);
        if (lane == 0) wl[wid * TOPK + r] = m;
        if (m != 0ULL && mymax == m) {              // unique owner pops
#pragma unroll
            for (int j = 0; j < 16; ++j) if (e[j] == m) e[j] = 0ULL;
            mymax = 0ULL;
#pragma unroll
            for (int j = 0; j < 16; ++j) mymax = umax64(mymax, e[j]);
        }
    }
    __syncthreads();

    // ---- wave 0 merges 144 partials + 9 fillers (pool == rounds 1-12) ----
    if (wid == 0) {
        unsigned long long f[4];
        f[0] = wl[lane];
        f[1] = wl[64 + lane];
        f[2] = (lane < 16) ? wl[128 + lane] : 0ULL;
        f[3] = (lane < TOPK) ? pack_key(-INFINITY, (unsigned)lane) : 0ULL;

        unsigned long long mx = 0ULL;
#pragma unroll
        for (int j = 0; j < 4; ++j) mx = umax64(mx, f[j]);

#pragma unroll
        for (int r = 0; r < TOPK; ++r) {
            unsigned long long m = wave_max64(mx);  // >0: fillers guarantee 9
            if (lane == 0) tidx[r] = ~(unsigned)(m & 0xFFFFFFFFu);
            if (mx == m) {                          // unique owner pops
#pragma unroll
                for (int j = 0; j < 4; ++j) if (f[j] == m) f[j] = 0ULL;
                mx = 0ULL;
#pragma unroll
                for (int j = 0; j < 4; ++j) mx = umax64(mx, f[j]);
            }
        }
    }
    __syncthreads();

    if (t < TOPK) {
        unsigned pi = tidx[t];
        ppy[t] = pts[2 * (size_t)pi];       // points col 0 ("cy" in reference)
        ppx[t] = pts[2 * (size_t)pi + 1];   // points col 1 ("cx")
    }
    __syncthreads();

    if (t == 0) {
        float4 g4 = ((const float4*)gtb)[g];
        float m0 = 0.0f, m1 = 0.0f;
#pragma unroll
        for (int k = 0; k < TOPK; ++k) { m0 += ppy[k]; m1 += ppx[k]; }
        m0 /= (float)TOPK; m1 /= (float)TOPK;

        float d0[TOPK], d1[TOPK];
        float a = 0.0f, bb = 0.0f, dd = 0.0f;
#pragma unroll
        for (int k = 0; k < TOPK; ++k) {
            d0[k] = ppy[k] - m0;
            d1[k] = ppx[k] - m1;
            a  += d0[k] * d0[k];
            bb += d0[k] * d1[k];
            dd += d1[k] * d1[k];
        }
        a /= (float)TOPK; bb /= (float)TOPK; dd /= (float)TOPK;
        float det  = a * dd - bb * bb;
        float rinv = 1.0f / (det + 1e-10f);

#pragma unroll
        for (int k = 0; k < TOPK; ++k) {
            float q = d0[k] * (dd * d0[k] - bb * d1[k])
                    + d1[k] * (a  * d1[k] - bb * d0[k]);
            float maha = q * rinv;
            float wt = expf(-0.5f * maha);
            bool valid = (ppx[k] - g4.x > 1e-10f) && (ppy[k] - g4.y > 1e-10f) &&
                         (g4.z - ppx[k] > 1e-10f) && (g4.w - ppy[k] > 1e-10f);
            float wv = valid ? wt : 0.0f;
            atomicMax((int*)&w[tidx[k]], __float_as_int(wv));
        }
    }
}

// ---------------------------------------------------------------------------
extern "C" void kernel_launch(void* const* d_in, const int* in_sizes, int n_in,
                              void* d_out, int out_size, void* d_ws, size_t ws_size,
                              hipStream_t stream) {
    const float* points  = (const float*)d_in[0];   // [65536,2]
    const float* cls     = (const float*)d_in[1];   // [65536,80]
    const float* preds   = (const float*)d_in[2];   // [65536,4]
    const float* gtb     = (const float*)d_in[3];   // [256,4]
    const int*   glab    = (const int*)d_in[4];     // [256]
    float* w = (float*)d_out;                       // [65536] f32

    char* ws = (char*)d_ws;
    unsigned long long* bucket = (unsigned long long*)ws;          // 33.55 MB
    size_t off = (size_t)NGT * NXB * SCAP * sizeof(unsigned long long);
    unsigned short* counts = (unsigned short*)(ws + off);          // 128 KB

    filter_kernel<<<dim3(NXB, NGT / GSLICE), 256, 0, stream>>>(
        preds, gtb, glab, cls, counts, bucket, w);
    select_kernel<<<NGT, 1024, 0, stream>>>(counts, bucket, points, gtb, w);
}